// Round 2
// baseline (697.633 us; speedup 1.0000x reference)
//
#include <hip/hip_runtime.h>

// InferenceDynamicEmbeddingCollection: out[f, i, :] = table[values[f^4, i] % VOCAB, :]
// F=8, B*L=81920 rows per feature, DIM=128 fp32. Pure memory-bound gather.

#define F_FEATS 8
#define BL 81920            // B*L = 4096*20
#define VOCAB 1000000
#define DIM 128
#define NROWS (F_FEATS * BL)  // 655360

typedef float vfloat4 __attribute__((ext_vector_type(4)));

// 32 lanes per row, float4 per lane -> 512 B per row.
// Block = 256 threads -> 8 rows per block.
__global__ __launch_bounds__(256) void gather_emb_kernel(
    const int* __restrict__ values,
    const float* __restrict__ table,
    float* __restrict__ out)
{
    const int lane = threadIdx.x & 31;
    const long long r = (long long)blockIdx.x * 8 + (threadIdx.x >> 5);
    if (r >= NROWS) return;

    const int f = (int)(r / BL);
    const int i = (int)(r - (long long)f * BL);
    const int sf = f ^ 4;  // feature permutation [4,5,6,7,0,1,2,3]

    const int v = values[(long long)sf * BL + i];
    const unsigned int slot = ((unsigned int)v) % (unsigned int)VOCAB;

    const vfloat4* __restrict__ src = (const vfloat4*)(table + (long long)slot * DIM);
    vfloat4* __restrict__ dst = (vfloat4*)(out + r * (long long)DIM);

    vfloat4 val = __builtin_nontemporal_load(src + lane);
    __builtin_nontemporal_store(val, dst + lane);
}

extern "C" void kernel_launch(void* const* d_in, const int* in_sizes, int n_in,
                              void* d_out, int out_size, void* d_ws, size_t ws_size,
                              hipStream_t stream)
{
    const int* values  = (const int*)d_in[0];
    const float* table = (const float*)d_in[1];
    float* out = (float*)d_out;

    const int blocks = NROWS / 8;  // 81920
    gather_emb_kernel<<<dim3(blocks), dim3(256), 0, stream>>>(values, table, out);
}